// Round 4
// baseline (304.579 us; speedup 1.0000x reference)
//
#include <hip/hip_runtime.h>

typedef __attribute__((ext_vector_type(8))) short s16x8;
typedef __attribute__((ext_vector_type(4))) float f32x4;
typedef __attribute__((ext_vector_type(4))) unsigned short u16x4;

#define AS1 __attribute__((address_space(1)))
#define AS3 __attribute__((address_space(3)))

__device__ __forceinline__ unsigned short f2bf(float f) {
    union { float f; unsigned u; } c; c.f = f;
    return (unsigned short)((c.u + 0x7FFFu + ((c.u >> 16) & 1u)) >> 16);
}

// ---------------- fp32 -> bf16 convert (vectorized) ----------------
__global__ void k_f32_to_bf16(const float* __restrict__ src,
                              unsigned short* __restrict__ dst, int n8) {
    int idx = blockIdx.x * 256 + threadIdx.x;
    int stride = gridDim.x * 256;
    for (int i = idx; i < n8; i += stride) {
        const float4* s = (const float4*)src + (size_t)i * 2;
        float4 a = s[0], b = s[1];
        s16x8 o;
        o[0] = (short)f2bf(a.x); o[1] = (short)f2bf(a.y);
        o[2] = (short)f2bf(a.z); o[3] = (short)f2bf(a.w);
        o[4] = (short)f2bf(b.x); o[5] = (short)f2bf(b.y);
        o[6] = (short)f2bf(b.z); o[7] = (short)f2bf(b.w);
        *((s16x8*)dst + i) = o;
    }
}

// -------- transpose + convert: W[K][N] fp32 -> Wt[N][K] bf16 --------
__global__ __launch_bounds__(256) void k_transpose_bf16(
    const float* __restrict__ W, unsigned short* __restrict__ Wt, int K, int N) {
    __shared__ float t[64][65];
    const int nk = K >> 6;
    const int k0 = (blockIdx.x % nk) << 6;
    const int n0 = (blockIdx.x / nk) << 6;
    const int tid = threadIdx.x;
#pragma unroll
    for (int it = 0; it < 4; it++) {
        int idx = tid + (it << 8);
        int r = idx >> 4, c4 = (idx & 15) << 2;
        float4 v = *(const float4*)(W + (size_t)(k0 + r) * N + n0 + c4);
        t[r][c4] = v.x; t[r][c4 + 1] = v.y; t[r][c4 + 2] = v.z; t[r][c4 + 3] = v.w;
    }
    __syncthreads();
#pragma unroll
    for (int it = 0; it < 2; it++) {
        int idx = tid + (it << 8);
        int rn = idx >> 3, c8 = (idx & 7) << 3;
        s16x8 o;
#pragma unroll
        for (int j = 0; j < 8; j++) o[j] = (short)f2bf(t[c8 + j][rn]);
        *(s16x8*)(Wt + (size_t)(n0 + rn) * K + k0 + c8) = o;
    }
}

// ------- GEMM, 256x128 tile, BK=64, 3-slot LDS ring, counted vmcnt -------
// 512 thr = 8 waves (2M x 4N); per-wave 128x32 out; 32 MFMA per barrier.
// Ring: compute slot c%3 while slot (c+2)%3 stages (region freed at step c-1).
// vmcnt(6) leaves next slot's 6 loads in flight (loads issued 2 steps ahead).
__global__ __launch_bounds__(512, 2) void k_gemm_ring(
    const unsigned short* __restrict__ A, const unsigned short* __restrict__ Bt,
    const float* __restrict__ bias, const float* __restrict__ wpe,
    unsigned short* __restrict__ Qo, unsigned short* __restrict__ Ko,
    unsigned short* __restrict__ Vo, float* __restrict__ Fo,
    int N, int K, int mode) {
    __shared__ __align__(16) char smem[147456];  // A: 3x32KB, B: 3x16KB
    const int tid = threadIdx.x;
    const int lane = tid & 63, wid = tid >> 6;
    const int wm = wid >> 2, wn = wid & 3;
    const int l15 = lane & 15, lg = lane >> 4;
    const int ntile = N >> 7;
    const int chunk = (int)gridDim.x >> 3;
    const int l = ((int)blockIdx.x & 7) * chunk + ((int)blockIdx.x >> 3);
    const int m0 = (l / ntile) << 8;
    const int n0 = (l % ntile) << 7;

    // staging: thread t covers row i*64 + t>>3, phys 16B-slot t&7 (linear dest);
    // source col pre-swizzled so LDS holds slot^(row&7) layout.
    const int trow = tid >> 3, tcol = tid & 7;
    const unsigned short* pA[4];
    const unsigned short* pB[2];
#pragma unroll
    for (int i = 0; i < 4; i++) {
        int r = (i << 6) + trow;
        pA[i] = A + (size_t)(m0 + r) * K + ((tcol ^ (r & 7)) << 3);
    }
#pragma unroll
    for (int i = 0; i < 2; i++) {
        int r = (i << 6) + trow;
        pB[i] = Bt + (size_t)(n0 + r) * K + ((tcol ^ (r & 7)) << 3);
    }
    const int dA = tid << 4;   // byte offset within slot per load-round

    // fragment ds_read byte offsets (within slot)
    int aoff[8][2], boff[2][2];
#pragma unroll
    for (int mi = 0; mi < 8; mi++) {
        int r = (wm << 7) + (mi << 4) + l15;
#pragma unroll
        for (int kk = 0; kk < 2; kk++)
            aoff[mi][kk] = r * 128 + (((lg + (kk << 2)) ^ (r & 7)) << 4);
    }
#pragma unroll
    for (int ni = 0; ni < 2; ni++) {
        int r = (wn << 5) + (ni << 4) + l15;
#pragma unroll
        for (int kk = 0; kk < 2; kk++)
            boff[ni][kk] = r * 128 + (((lg + (kk << 2)) ^ (r & 7)) << 4);
    }

    const f32x4 vzero = {0.f, 0.f, 0.f, 0.f};
    f32x4 acc[8][2];
#pragma unroll
    for (int i = 0; i < 8; i++) {
        acc[i][0] = vzero; acc[i][1] = vzero;
    }

    auto stage = [&](int slot) {
        char* ab = smem + slot * 32768;
        char* bb = smem + 98304 + slot * 16384;
#pragma unroll
        for (int i = 0; i < 4; i++) {
            __builtin_amdgcn_global_load_lds((const AS1 void*)pA[i],
                                             (AS3 void*)(ab + (i << 13) + dA),
                                             16, 0, 0);
            pA[i] += 64;
        }
#pragma unroll
        for (int i = 0; i < 2; i++) {
            __builtin_amdgcn_global_load_lds((const AS1 void*)pB[i],
                                             (AS3 void*)(bb + (i << 13) + dA),
                                             16, 0, 0);
            pB[i] += 64;
        }
    };

    const int NT = K >> 6;
    stage(0);
    stage(1);

    for (int c = 0; c < NT; c++) {
        // counted wait: slot c arrived (issued 2 steps ago); slot c+1 may fly.
        if (c < NT - 1)
            asm volatile("s_waitcnt vmcnt(6)\ns_barrier" ::: "memory");
        else
            asm volatile("s_waitcnt vmcnt(0)\ns_barrier" ::: "memory");
        const int cs = c % 3;
        const char* ab = smem + cs * 32768;
        const char* bb = smem + 98304 + cs * 16384;

        // kk = 0 reads, then prefetch-stage, then MFMA
        s16x8 af[8], bfr[2];
#pragma unroll
        for (int mi = 0; mi < 8; mi++)
            af[mi] = *(const s16x8*)(ab + aoff[mi][0]);
#pragma unroll
        for (int ni = 0; ni < 2; ni++)
            bfr[ni] = *(const s16x8*)(bb + boff[ni][0]);
        if (c + 2 < NT) stage((c + 2) % 3);
        __builtin_amdgcn_s_setprio(1);
#pragma unroll
        for (int mi = 0; mi < 8; mi++)
#pragma unroll
            for (int ni = 0; ni < 2; ni++)
                acc[mi][ni] = __builtin_amdgcn_mfma_f32_16x16x32_bf16(
                    af[mi], bfr[ni], acc[mi][ni], 0, 0, 0);
        __builtin_amdgcn_s_setprio(0);
        // kk = 1
#pragma unroll
        for (int mi = 0; mi < 8; mi++)
            af[mi] = *(const s16x8*)(ab + aoff[mi][1]);
#pragma unroll
        for (int ni = 0; ni < 2; ni++)
            bfr[ni] = *(const s16x8*)(bb + boff[ni][1]);
        __builtin_amdgcn_s_setprio(1);
#pragma unroll
        for (int mi = 0; mi < 8; mi++)
#pragma unroll
            for (int ni = 0; ni < 2; ni++)
                acc[mi][ni] = __builtin_amdgcn_mfma_f32_16x16x32_bf16(
                    af[mi], bfr[ni], acc[mi][ni], 0, 0, 0);
        __builtin_amdgcn_s_setprio(0);
    }

    if (mode == 0) {
#pragma unroll
        for (int ni = 0; ni < 2; ni++) {
            int n = n0 + (wn << 5) + (ni << 4) + l15;
            int which = n >> 10, rem = n & 1023;
            int h = rem >> 6, s = rem & 63;
            unsigned short* outp = (which == 0) ? Qo : ((which == 1) ? Ko : Vo);
            float bv = bias[n];
#pragma unroll
            for (int mi = 0; mi < 8; mi++) {
#pragma unroll
                for (int j = 0; j < 4; j++) {
                    int m = m0 + (wm << 7) + (mi << 4) + (lg << 2) + j;
                    int b = m >> 11, t = m & 2047;
                    float v = acc[mi][ni][j] + bv;
                    if (which < 2) v += wpe[((((t << 4) + h) & 2047) << 6) + s];
                    outp[(size_t)(b * 16 + h) * 131072 + (size_t)t * 64 + s] = f2bf(v);
                }
            }
        }
    } else {
#pragma unroll
        for (int ni = 0; ni < 2; ni++) {
            int n = n0 + (wn << 5) + (ni << 4) + l15;
            float bv = bias[n];
#pragma unroll
            for (int mi = 0; mi < 8; mi++) {
#pragma unroll
                for (int j = 0; j < 4; j++) {
                    int m = m0 + (wm << 7) + (mi << 4) + (lg << 2) + j;
                    Fo[(size_t)m * N + n] = acc[mi][ni][j] + bv;
                }
            }
        }
    }
}

// ---------------- flash attention (causal), swapped-QK^T ----------------
// grid: 2048 blocks = 64 bh x 32 q-tiles (64 rows). Mapping: xcd=bid&7 so all
// 32 blocks of a bh land on one XCD (K/V 512KB x 8 bh = 4MB ~ L2); qt-major
// DESCENDING so the longest blocks start first. 6 blocks/CU (LDS 24KB).
__global__ __launch_bounds__(256, 6) void k_attn(
    const unsigned short* __restrict__ Qg, const unsigned short* __restrict__ Kg,
    const unsigned short* __restrict__ Vg, unsigned short* __restrict__ Yg) {
    __shared__ unsigned short Klds[4096];    // [64 kv][64 s], swizzled (8KB)
    __shared__ unsigned short Vtlds[4096];   // [64 s][64 kv], fv-swizzled (8KB)
    __shared__ unsigned short Plds[4096];    // per-wave [16 q][64 kv] (8KB)
    const int tid = threadIdx.x, lane = tid & 63, wid = tid >> 6;
    const int l15 = lane & 15, lg = lane >> 4;
    const int lr = lane >> 3, ls = lane & 7;
    const int p = blockIdx.x;
    const int xcd = p & 7, rank = p >> 3;
    const int qt = 31 - (rank >> 3);          // descending work
    const int bh = ((rank & 7) << 3) | xcd;   // bh colocated on xcd
    const int b = bh >> 4, h = bh & 15;
    const size_t base = (size_t)bh * 131072;
    const int q0 = qt << 6;
    const int qrow = q0 + (wid << 4) + l15;
    const int vkv4 = (tid >> 4) << 2;   // 0..60
    const int vd4 = (tid & 15) << 2;    // 0..60

    const f32x4 vzero = {0.f, 0.f, 0.f, 0.f};

    s16x8 qf[2];
#pragma unroll
    for (int kk = 0; kk < 2; kk++)
        qf[kk] = *(const s16x8*)(Qg + base + (size_t)qrow * 64 +
                                 (kk << 5) + (lg << 3));

    f32x4 o[4];
#pragma unroll
    for (int i = 0; i < 4; i++) o[i] = vzero;
    float mrun = -3.0e38f, lrun = 0.f;   // mrun in RAW score domain

    const int nt = qt + 1;
    for (int tI = 0; tI < nt; tI++) {
        const int kv0 = tI << 6;
        // stage K (async global->LDS, pre-swizzled source)
#pragma unroll
        for (int i = 0; i < 2; i++) {
            int r = (wid << 4) + (i << 3) + lr;
            int sl = (ls ^ (r & 7)) << 3;
            __builtin_amdgcn_global_load_lds(
                (const AS1 void*)(Kg + base + (size_t)(kv0 + r) * 64 + sl),
                (AS3 void*)(Klds + (wid << 10) + (i << 9)), 16, 0, 0);
        }
        // stage V transposed: 4x4 reg mini-transpose -> ds_write_b64
        // fv(row) spreads the 16 writes of a lane-group across banks
        {
            u16x4 vv[4];
#pragma unroll
            for (int r = 0; r < 4; r++)
                vv[r] = *(const u16x4*)(Vg + base +
                                        (size_t)(kv0 + vkv4 + r) * 64 + vd4);
#pragma unroll
            for (int dj = 0; dj < 4; dj++) {
                int row = vd4 + dj;
                int fv = (row ^ (row >> 3)) & 7;
                unsigned long long pk =
                    (unsigned long long)vv[0][dj] |
                    ((unsigned long long)vv[1][dj] << 16) |
                    ((unsigned long long)vv[2][dj] << 32) |
                    ((unsigned long long)vv[3][dj] << 48);
                *(unsigned long long*)((char*)Vtlds + row * 128 +
                                       ((((vkv4 >> 3) ^ fv) & 7) << 4) +
                                       ((vkv4 & 7) << 1)) = pk;
            }
        }
        __syncthreads();

        // S^T = K * Q^T  (acc: col=q=l15, row=kv=lg*4+j)
        f32x4 sacc[4];
#pragma unroll
        for (int i = 0; i < 4; i++) sacc[i] = vzero;
        __builtin_amdgcn_s_setprio(1);
#pragma unroll
        for (int kk = 0; kk < 2; kk++) {
            s16x8 kf[4];
#pragma unroll
            for (int ki = 0; ki < 4; ki++) {
                int row = (ki << 4) + l15;
                int slot = lg + (kk << 2);
                kf[ki] = *(const s16x8*)((const char*)Klds + row * 128 +
                                         ((slot ^ (row & 7)) << 4));
            }
#pragma unroll
            for (int ki = 0; ki < 4; ki++)
                sacc[ki] = __builtin_amdgcn_mfma_f32_16x16x32_bf16(
                    kf[ki], qf[kk], sacc[ki], 0, 0, 0);
        }
        __builtin_amdgcn_s_setprio(0);

        // online softmax in raw-score domain (scale folded into exp arg)
        float tm = -3.0e38f;
        if (tI == nt - 1) {   // diagonal tile: causal mask
#pragma unroll
            for (int ki = 0; ki < 4; ki++) {
#pragma unroll
                for (int j = 0; j < 4; j++) {
                    int kvg = kv0 + (ki << 4) + (lg << 2) + j;
                    float sv = sacc[ki][j];
                    if (kvg > qrow) sv = -3.0e38f;
                    sacc[ki][j] = sv;
                    tm = fmaxf(tm, sv);
                }
            }
        } else {
#pragma unroll
            for (int ki = 0; ki < 4; ki++) {
#pragma unroll
                for (int j = 0; j < 4; j++) tm = fmaxf(tm, sacc[ki][j]);
            }
        }
        tm = fmaxf(tm, __shfl_xor(tm, 16, 64));
        tm = fmaxf(tm, __shfl_xor(tm, 32, 64));
        float mnew = fmaxf(mrun, tm);
        float rfac = __expf((mrun - mnew) * 0.125f);
        float m8 = mnew * 0.125f;
        mrun = mnew;
        float ps = 0.f;
#pragma unroll
        for (int ki = 0; ki < 4; ki++) {
#pragma unroll
            for (int j = 0; j < 4; j++) {
                float pv = __expf(__builtin_fmaf(sacc[ki][j], 0.125f, -m8));
                sacc[ki][j] = pv;
                ps += pv;
            }
        }
        ps += __shfl_xor(ps, 16, 64);
        ps += __shfl_xor(ps, 32, 64);
        lrun = lrun * rfac + ps;
        // rescale O (row q = lg*4+j needs column-q's factor)
#pragma unroll
        for (int j = 0; j < 4; j++) {
            float rj = __shfl(rfac, (lane & 48) | ((lg << 2) + j), 64);
#pragma unroll
            for (int si = 0; si < 4; si++) o[si][j] *= rj;
        }
        // pack P -> per-wave LDS (swizzled), b64 writes
#pragma unroll
        for (int ki = 0; ki < 4; ki++) {
            unsigned long long pk =
                (unsigned long long)f2bf(sacc[ki][0]) |
                ((unsigned long long)f2bf(sacc[ki][1]) << 16) |
                ((unsigned long long)f2bf(sacc[ki][2]) << 32) |
                ((unsigned long long)f2bf(sacc[ki][3]) << 48);
            int kvl = (ki << 4) + (lg << 2);
            int slot = kvl >> 3;
            *(unsigned long long*)((char*)Plds + (wid << 11) + l15 * 128 +
                                   ((slot ^ (l15 & 7)) << 4) +
                                   ((kvl & 7) << 1)) = pk;
        }

        // O += P * V
        __builtin_amdgcn_s_setprio(1);
#pragma unroll
        for (int kk = 0; kk < 2; kk++) {
            s16x8 vf[4];
#pragma unroll
            for (int si = 0; si < 4; si++) {
                int row = (si << 4) + l15;
                int slot = lg + (kk << 2);
                int fv = (row ^ (row >> 3)) & 7;
                vf[si] = *(const s16x8*)((const char*)Vtlds + row * 128 +
                                         (((slot ^ fv) & 7) << 4));
            }
            int prow = l15;
            int slot = lg + (kk << 2);
            s16x8 pf = *(const s16x8*)((const char*)Plds + (wid << 11) +
                                       prow * 128 + ((slot ^ (prow & 7)) << 4));
#pragma unroll
            for (int si = 0; si < 4; si++)
                o[si] = __builtin_amdgcn_mfma_f32_16x16x32_bf16(
                    pf, vf[si], o[si], 0, 0, 0);
        }
        __builtin_amdgcn_s_setprio(0);
        __syncthreads();
    }

    // epilogue: divide by l, write y[b][t][h*64+s] bf16
#pragma unroll
    for (int j = 0; j < 4; j++) {
        float lv = __shfl(lrun, (lane & 48) | ((lg << 2) + j), 64);
        float linv = 1.0f / lv;
        int qg = q0 + (wid << 4) + (lg << 2) + j;
        size_t rowoff = ((size_t)b * 2048 + qg) * 1024 + (h << 6);
#pragma unroll
        for (int si = 0; si < 4; si++) {
            int sg = (si << 4) + l15;
            Yg[rowoff + sg] = f2bf(o[si][j] * linv);
        }
    }
}

extern "C" void kernel_launch(void* const* d_in, const int* in_sizes, int n_in,
                              void* d_out, int out_size, void* d_ws, size_t ws_size,
                              hipStream_t stream) {
    const float* x   = (const float*)d_in[0];
    const float* w1  = (const float*)d_in[1];
    const float* b1  = (const float*)d_in[2];
    const float* w2  = (const float*)d_in[3];
    const float* b2  = (const float*)d_in[4];
    const float* wpe = (const float*)d_in[5];
    float* out = (float*)d_out;

    char* ws = (char*)d_ws;
    unsigned short* xb  = (unsigned short*)(ws);              // 16.78 MB
    unsigned short* w1t = (unsigned short*)(ws + 16777216);   //  6.29 MB
    unsigned short* w2t = (unsigned short*)(ws + 23068672);   //  2.10 MB
    unsigned short* Qb  = (unsigned short*)(ws + 25165824);   // 16.78 MB
    unsigned short* Kb  = (unsigned short*)(ws + 41943040);   // 16.78 MB
    unsigned short* Vb  = (unsigned short*)(ws + 58720256);   // 16.78 MB
    unsigned short* Yb  = (unsigned short*)(ws + 75497472);   // 16.78 MB -> 92.3 MB total

    k_f32_to_bf16<<<2048, 256, 0, stream>>>(x, xb, 8388608 / 8);
    k_transpose_bf16<<<768, 256, 0, stream>>>(w1, w1t, 1024, 3072);
    k_transpose_bf16<<<256, 256, 0, stream>>>(w2, w2t, 1024, 1024);
    k_gemm_ring<<<768, 512, 0, stream>>>(xb, w1t, b1, wpe, Qb, Kb, Vb,
                                         nullptr, 3072, 1024, 0);
    k_attn<<<2048, 256, 0, stream>>>(Qb, Kb, Vb, Yb);
    k_gemm_ring<<<256, 512, 0, stream>>>(Yb, w2t, b2, nullptr, nullptr, nullptr,
                                         nullptr, out, 1024, 1024, 1);
}

// Round 5
// 301.035 us; speedup vs baseline: 1.0118x; 1.0118x over previous
//
#include <hip/hip_runtime.h>

typedef __attribute__((ext_vector_type(8))) short s16x8;
typedef __attribute__((ext_vector_type(4))) float f32x4;
typedef __attribute__((ext_vector_type(4))) unsigned short u16x4;

#define AS1 __attribute__((address_space(1)))
#define AS3 __attribute__((address_space(3)))

__device__ __forceinline__ unsigned short f2bf(float f) {
    union { float f; unsigned u; } c; c.f = f;
    return (unsigned short)((c.u + 0x7FFFu + ((c.u >> 16) & 1u)) >> 16);
}

// ---------------- fp32 -> bf16 convert (vectorized) ----------------
__global__ void k_f32_to_bf16(const float* __restrict__ src,
                              unsigned short* __restrict__ dst, int n8) {
    int idx = blockIdx.x * 256 + threadIdx.x;
    int stride = gridDim.x * 256;
    for (int i = idx; i < n8; i += stride) {
        const float4* s = (const float4*)src + (size_t)i * 2;
        float4 a = s[0], b = s[1];
        s16x8 o;
        o[0] = (short)f2bf(a.x); o[1] = (short)f2bf(a.y);
        o[2] = (short)f2bf(a.z); o[3] = (short)f2bf(a.w);
        o[4] = (short)f2bf(b.x); o[5] = (short)f2bf(b.y);
        o[6] = (short)f2bf(b.z); o[7] = (short)f2bf(b.w);
        *((s16x8*)dst + i) = o;
    }
}

// -------- transpose + convert: W[K][N] fp32 -> Wt[N][K] bf16 --------
__global__ __launch_bounds__(256) void k_transpose_bf16(
    const float* __restrict__ W, unsigned short* __restrict__ Wt, int K, int N) {
    __shared__ float t[64][65];
    const int nk = K >> 6;
    const int k0 = (blockIdx.x % nk) << 6;
    const int n0 = (blockIdx.x / nk) << 6;
    const int tid = threadIdx.x;
#pragma unroll
    for (int it = 0; it < 4; it++) {
        int idx = tid + (it << 8);
        int r = idx >> 4, c4 = (idx & 15) << 2;
        float4 v = *(const float4*)(W + (size_t)(k0 + r) * N + n0 + c4);
        t[r][c4] = v.x; t[r][c4 + 1] = v.y; t[r][c4 + 2] = v.z; t[r][c4 + 3] = v.w;
    }
    __syncthreads();
#pragma unroll
    for (int it = 0; it < 2; it++) {
        int idx = tid + (it << 8);
        int rn = idx >> 3, c8 = (idx & 7) << 3;
        s16x8 o;
#pragma unroll
        for (int j = 0; j < 8; j++) o[j] = (short)f2bf(t[c8 + j][rn]);
        *(s16x8*)(Wt + (size_t)(n0 + rn) * K + k0 + c8) = o;
    }
}

// ---- GEMM 256x128, BK=64, 3-slot ring, 2-phase/step 8-phase rhythm ----
// 512 thr = 8 waves (4M x 2N), wave tile 64x64 (acc 4x4).
// Per K-step: boundary {vmcnt(6); barrier}; phase0 {12 ds_read | stage 1/2 of
// slot c+2 | 16 MFMA (ni 0,1) | barrier}; phase1 {4 ds_read | stage 2/2 |
// 16 MFMA (ni 2,3)}. vmcnt never drains to 0 in the main loop (T3+T4).
__global__ __launch_bounds__(512, 2) void k_gemm_ring(
    const unsigned short* __restrict__ A, const unsigned short* __restrict__ Bt,
    const float* __restrict__ bias, const float* __restrict__ wpe,
    unsigned short* __restrict__ Qo, unsigned short* __restrict__ Ko,
    unsigned short* __restrict__ Vo, float* __restrict__ Fo,
    int N, int K, int mode) {
    __shared__ __align__(16) char smem[147456];  // A: 3x32KB @0, B: 3x16KB @98304
    const int tid = threadIdx.x;
    const int lane = tid & 63, wid = tid >> 6;
    const int wm = wid >> 1, wn = wid & 1;
    const int l15 = lane & 15, lg = lane >> 4;
    const int ntile = N >> 7;
    const int chunk = (int)gridDim.x >> 3;
    const int l = ((int)blockIdx.x & 7) * chunk + ((int)blockIdx.x >> 3);
    const int m0 = (l / ntile) << 8;
    const int n0 = (l % ntile) << 7;

    // staging: thread t covers row trow, phys 16B-slot tcol (linear LDS dest);
    // source col pre-swizzled so LDS holds slot^(row&7) layout.
    const int trow = tid >> 3, tcol = tid & 7;
    const unsigned short* pA[4];
    const unsigned short* pB[2];
#pragma unroll
    for (int i = 0; i < 4; i++) {
        int r = (i << 6) + trow;
        pA[i] = A + (size_t)(m0 + r) * K + ((tcol ^ (r & 7)) << 3);
    }
#pragma unroll
    for (int i = 0; i < 2; i++) {
        int r = (i << 6) + trow;
        pB[i] = Bt + (size_t)(n0 + r) * K + ((tcol ^ (r & 7)) << 3);
    }
    const int dA = tid << 4;

    // fragment ds_read byte offsets (within slot)
    int aoff[4][2], boff[4][2];
#pragma unroll
    for (int mi = 0; mi < 4; mi++) {
        int r = (wm << 6) + (mi << 4) + l15;
#pragma unroll
        for (int kk = 0; kk < 2; kk++)
            aoff[mi][kk] = r * 128 + (((lg + (kk << 2)) ^ (r & 7)) << 4);
    }
#pragma unroll
    for (int ni = 0; ni < 4; ni++) {
        int r = (wn << 6) + (ni << 4) + l15;
#pragma unroll
        for (int kk = 0; kk < 2; kk++)
            boff[ni][kk] = r * 128 + (((lg + (kk << 2)) ^ (r & 7)) << 4);
    }

    const f32x4 vzero = {0.f, 0.f, 0.f, 0.f};
    f32x4 acc[4][4];
#pragma unroll
    for (int i = 0; i < 4; i++)
#pragma unroll
        for (int j = 0; j < 4; j++) acc[i][j] = vzero;

    auto stageH0 = [&](int slot) {   // A rows 0..127 + B rows 0..63
        char* ab = smem + slot * 32768;
        char* bb = smem + 98304 + slot * 16384;
        __builtin_amdgcn_global_load_lds((const AS1 void*)pA[0],
                                         (AS3 void*)(ab + dA), 16, 0, 0);
        pA[0] += 64;
        __builtin_amdgcn_global_load_lds((const AS1 void*)pA[1],
                                         (AS3 void*)(ab + 8192 + dA), 16, 0, 0);
        pA[1] += 64;
        __builtin_amdgcn_global_load_lds((const AS1 void*)pB[0],
                                         (AS3 void*)(bb + dA), 16, 0, 0);
        pB[0] += 64;
    };
    auto stageH1 = [&](int slot) {   // A rows 128..255 + B rows 64..127
        char* ab = smem + slot * 32768;
        char* bb = smem + 98304 + slot * 16384;
        __builtin_amdgcn_global_load_lds((const AS1 void*)pA[2],
                                         (AS3 void*)(ab + 16384 + dA), 16, 0, 0);
        pA[2] += 64;
        __builtin_amdgcn_global_load_lds((const AS1 void*)pA[3],
                                         (AS3 void*)(ab + 24576 + dA), 16, 0, 0);
        pA[3] += 64;
        __builtin_amdgcn_global_load_lds((const AS1 void*)pB[1],
                                         (AS3 void*)(bb + 8192 + dA), 16, 0, 0);
        pB[1] += 64;
    };

    const int NT = K >> 6;
    stageH0(0); stageH1(0);
    stageH0(1); stageH1(1);

    for (int c = 0; c < NT; c++) {
        // boundary: slot c landed; slot c+1's 6 loads may stay in flight
        if (c < NT - 1)
            asm volatile("s_waitcnt vmcnt(6)" ::: "memory");
        else
            asm volatile("s_waitcnt vmcnt(0)" ::: "memory");
        __builtin_amdgcn_s_barrier();
        const int cs = c % 3;
        const char* ab = smem + cs * 32768;
        const char* bb = smem + 98304 + cs * 16384;
        const bool pf = (c + 2 < NT);
        const int ps = (c + 2) % 3;

        // ---- phase 0: A-frags + B ni{0,1}; stage half0; MFMA ni{0,1} ----
        s16x8 af[4][2], bf0[2][2];
#pragma unroll
        for (int mi = 0; mi < 4; mi++)
#pragma unroll
            for (int kk = 0; kk < 2; kk++)
                af[mi][kk] = *(const s16x8*)(ab + aoff[mi][kk]);
#pragma unroll
        for (int ni = 0; ni < 2; ni++)
#pragma unroll
            for (int kk = 0; kk < 2; kk++)
                bf0[ni][kk] = *(const s16x8*)(bb + boff[ni][kk]);
        if (pf) stageH0(ps);
        __builtin_amdgcn_s_setprio(1);
#pragma unroll
        for (int kk = 0; kk < 2; kk++)
#pragma unroll
            for (int mi = 0; mi < 4; mi++)
#pragma unroll
                for (int ni = 0; ni < 2; ni++)
                    acc[mi][ni] = __builtin_amdgcn_mfma_f32_16x16x32_bf16(
                        af[mi][kk], bf0[ni][kk], acc[mi][ni], 0, 0, 0);
        __builtin_amdgcn_s_setprio(0);
        __builtin_amdgcn_s_barrier();

        // ---- phase 1: B ni{2,3}; stage half1; MFMA ni{2,3} (af reused) ----
        s16x8 bf1[2][2];
#pragma unroll
        for (int ni = 0; ni < 2; ni++)
#pragma unroll
            for (int kk = 0; kk < 2; kk++)
                bf1[ni][kk] = *(const s16x8*)(bb + boff[2 + ni][kk]);
        if (pf) stageH1(ps);
        __builtin_amdgcn_s_setprio(1);
#pragma unroll
        for (int kk = 0; kk < 2; kk++)
#pragma unroll
            for (int mi = 0; mi < 4; mi++)
#pragma unroll
                for (int ni = 0; ni < 2; ni++)
                    acc[mi][2 + ni] = __builtin_amdgcn_mfma_f32_16x16x32_bf16(
                        af[mi][kk], bf1[ni][kk], acc[mi][2 + ni], 0, 0, 0);
        __builtin_amdgcn_s_setprio(0);
    }

    if (mode == 0) {
#pragma unroll
        for (int ni = 0; ni < 4; ni++) {
            int n = n0 + (wn << 6) + (ni << 4) + l15;
            int which = n >> 10, rem = n & 1023;
            int h = rem >> 6, s = rem & 63;
            unsigned short* outp = (which == 0) ? Qo : ((which == 1) ? Ko : Vo);
            float bv = bias[n];
#pragma unroll
            for (int mi = 0; mi < 4; mi++) {
#pragma unroll
                for (int j = 0; j < 4; j++) {
                    int m = m0 + (wm << 6) + (mi << 4) + (lg << 2) + j;
                    int b = m >> 11, t = m & 2047;
                    float v = acc[mi][ni][j] + bv;
                    if (which < 2) v += wpe[((((t << 4) + h) & 2047) << 6) + s];
                    outp[(size_t)(b * 16 + h) * 131072 + (size_t)t * 64 + s] = f2bf(v);
                }
            }
        }
    } else {
#pragma unroll
        for (int ni = 0; ni < 4; ni++) {
            int n = n0 + (wn << 6) + (ni << 4) + l15;
            float bv = bias[n];
#pragma unroll
            for (int mi = 0; mi < 4; mi++) {
#pragma unroll
                for (int j = 0; j < 4; j++) {
                    int m = m0 + (wm << 6) + (mi << 4) + (lg << 2) + j;
                    Fo[(size_t)m * N + n] = acc[mi][ni][j] + bv;
                }
            }
        }
    }
}

// ---------------- flash attention (causal), swapped-QK^T ----------------
// grid: 2048 blocks = 64 bh x 32 q-tiles (64 rows). Mapping: xcd=bid&7 so all
// 32 blocks of a bh land on one XCD (K/V 512KB x 8 bh = 4MB ~ L2); qt-major
// DESCENDING so the longest blocks start first. 6 blocks/CU (LDS 24KB).
__global__ __launch_bounds__(256, 6) void k_attn(
    const unsigned short* __restrict__ Qg, const unsigned short* __restrict__ Kg,
    const unsigned short* __restrict__ Vg, unsigned short* __restrict__ Yg) {
    __shared__ unsigned short Klds[4096];    // [64 kv][64 s], swizzled (8KB)
    __shared__ unsigned short Vtlds[4096];   // [64 s][64 kv], fv-swizzled (8KB)
    __shared__ unsigned short Plds[4096];    // per-wave [16 q][64 kv] (8KB)
    const int tid = threadIdx.x, lane = tid & 63, wid = tid >> 6;
    const int l15 = lane & 15, lg = lane >> 4;
    const int lr = lane >> 3, ls = lane & 7;
    const int p = blockIdx.x;
    const int xcd = p & 7, rank = p >> 3;
    const int qt = 31 - (rank >> 3);          // descending work
    const int bh = ((rank & 7) << 3) | xcd;   // bh colocated on xcd
    const int b = bh >> 4, h = bh & 15;
    const size_t base = (size_t)bh * 131072;
    const int q0 = qt << 6;
    const int qrow = q0 + (wid << 4) + l15;
    const int vkv4 = (tid >> 4) << 2;   // 0..60
    const int vd4 = (tid & 15) << 2;    // 0..60

    const f32x4 vzero = {0.f, 0.f, 0.f, 0.f};

    s16x8 qf[2];
#pragma unroll
    for (int kk = 0; kk < 2; kk++)
        qf[kk] = *(const s16x8*)(Qg + base + (size_t)qrow * 64 +
                                 (kk << 5) + (lg << 3));

    f32x4 o[4];
#pragma unroll
    for (int i = 0; i < 4; i++) o[i] = vzero;
    float mrun = -3.0e38f, lrun = 0.f;   // mrun in RAW score domain

    const int nt = qt + 1;
    for (int tI = 0; tI < nt; tI++) {
        const int kv0 = tI << 6;
        // stage K (async global->LDS, pre-swizzled source)
#pragma unroll
        for (int i = 0; i < 2; i++) {
            int r = (wid << 4) + (i << 3) + lr;
            int sl = (ls ^ (r & 7)) << 3;
            __builtin_amdgcn_global_load_lds(
                (const AS1 void*)(Kg + base + (size_t)(kv0 + r) * 64 + sl),
                (AS3 void*)(Klds + (wid << 10) + (i << 9)), 16, 0, 0);
        }
        // stage V transposed: 4x4 reg mini-transpose -> ds_write_b64
        // fv(row) spreads the 16 writes of a lane-group across banks
        {
            u16x4 vv[4];
#pragma unroll
            for (int r = 0; r < 4; r++)
                vv[r] = *(const u16x4*)(Vg + base +
                                        (size_t)(kv0 + vkv4 + r) * 64 + vd4);
#pragma unroll
            for (int dj = 0; dj < 4; dj++) {
                int row = vd4 + dj;
                int fv = (row ^ (row >> 3)) & 7;
                unsigned long long pk =
                    (unsigned long long)vv[0][dj] |
                    ((unsigned long long)vv[1][dj] << 16) |
                    ((unsigned long long)vv[2][dj] << 32) |
                    ((unsigned long long)vv[3][dj] << 48);
                *(unsigned long long*)((char*)Vtlds + row * 128 +
                                       ((((vkv4 >> 3) ^ fv) & 7) << 4) +
                                       ((vkv4 & 7) << 1)) = pk;
            }
        }
        __syncthreads();

        // S^T = K * Q^T  (acc: col=q=l15, row=kv=lg*4+j)
        f32x4 sacc[4];
#pragma unroll
        for (int i = 0; i < 4; i++) sacc[i] = vzero;
        __builtin_amdgcn_s_setprio(1);
#pragma unroll
        for (int kk = 0; kk < 2; kk++) {
            s16x8 kf[4];
#pragma unroll
            for (int ki = 0; ki < 4; ki++) {
                int row = (ki << 4) + l15;
                int slot = lg + (kk << 2);
                kf[ki] = *(const s16x8*)((const char*)Klds + row * 128 +
                                         ((slot ^ (row & 7)) << 4));
            }
#pragma unroll
            for (int ki = 0; ki < 4; ki++)
                sacc[ki] = __builtin_amdgcn_mfma_f32_16x16x32_bf16(
                    kf[ki], qf[kk], sacc[ki], 0, 0, 0);
        }
        __builtin_amdgcn_s_setprio(0);

        // online softmax in raw-score domain (scale folded into exp arg)
        float tm = -3.0e38f;
        if (tI == nt - 1) {   // diagonal tile: causal mask
#pragma unroll
            for (int ki = 0; ki < 4; ki++) {
#pragma unroll
                for (int j = 0; j < 4; j++) {
                    int kvg = kv0 + (ki << 4) + (lg << 2) + j;
                    float sv = sacc[ki][j];
                    if (kvg > qrow) sv = -3.0e38f;
                    sacc[ki][j] = sv;
                    tm = fmaxf(tm, sv);
                }
            }
        } else {
#pragma unroll
            for (int ki = 0; ki < 4; ki++) {
#pragma unroll
                for (int j = 0; j < 4; j++) tm = fmaxf(tm, sacc[ki][j]);
            }
        }
        tm = fmaxf(tm, __shfl_xor(tm, 16, 64));
        tm = fmaxf(tm, __shfl_xor(tm, 32, 64));
        float mnew = fmaxf(mrun, tm);
        float rfac = __expf((mrun - mnew) * 0.125f);
        float m8 = mnew * 0.125f;
        mrun = mnew;
        float ps = 0.f;
#pragma unroll
        for (int ki = 0; ki < 4; ki++) {
#pragma unroll
            for (int j = 0; j < 4; j++) {
                float pv = __expf(__builtin_fmaf(sacc[ki][j], 0.125f, -m8));
                sacc[ki][j] = pv;
                ps += pv;
            }
        }
        ps += __shfl_xor(ps, 16, 64);
        ps += __shfl_xor(ps, 32, 64);
        lrun = lrun * rfac + ps;
        // rescale O (row q = lg*4+j needs column-q's factor)
#pragma unroll
        for (int j = 0; j < 4; j++) {
            float rj = __shfl(rfac, (lane & 48) | ((lg << 2) + j), 64);
#pragma unroll
            for (int si = 0; si < 4; si++) o[si][j] *= rj;
        }
        // pack P -> per-wave LDS (swizzled), b64 writes
#pragma unroll
        for (int ki = 0; ki < 4; ki++) {
            unsigned long long pk =
                (unsigned long long)f2bf(sacc[ki][0]) |
                ((unsigned long long)f2bf(sacc[ki][1]) << 16) |
                ((unsigned long long)f2bf(sacc[ki][2]) << 32) |
                ((unsigned long long)f2bf(sacc[ki][3]) << 48);
            int kvl = (ki << 4) + (lg << 2);
            int slot = kvl >> 3;
            *(unsigned long long*)((char*)Plds + (wid << 11) + l15 * 128 +
                                   ((slot ^ (l15 & 7)) << 4) +
                                   ((kvl & 7) << 1)) = pk;
        }

        // O += P * V
        __builtin_amdgcn_s_setprio(1);
#pragma unroll
        for (int kk = 0; kk < 2; kk++) {
            s16x8 vf[4];
#pragma unroll
            for (int si = 0; si < 4; si++) {
                int row = (si << 4) + l15;
                int slot = lg + (kk << 2);
                int fv = (row ^ (row >> 3)) & 7;
                vf[si] = *(const s16x8*)((const char*)Vtlds + row * 128 +
                                         (((slot ^ fv) & 7) << 4));
            }
            int prow = l15;
            int slot = lg + (kk << 2);
            s16x8 pf = *(const s16x8*)((const char*)Plds + (wid << 11) +
                                       prow * 128 + ((slot ^ (prow & 7)) << 4));
#pragma unroll
            for (int si = 0; si < 4; si++)
                o[si] = __builtin_amdgcn_mfma_f32_16x16x32_bf16(
                    pf, vf[si], o[si], 0, 0, 0);
        }
        __builtin_amdgcn_s_setprio(0);
        __syncthreads();
    }

    // epilogue: divide by l, write y[b][t][h*64+s] bf16
#pragma unroll
    for (int j = 0; j < 4; j++) {
        float lv = __shfl(lrun, (lane & 48) | ((lg << 2) + j), 64);
        float linv = 1.0f / lv;
        int qg = q0 + (wid << 4) + (lg << 2) + j;
        size_t rowoff = ((size_t)b * 2048 + qg) * 1024 + (h << 6);
#pragma unroll
        for (int si = 0; si < 4; si++) {
            int sg = (si << 4) + l15;
            Yg[rowoff + sg] = f2bf(o[si][j] * linv);
        }
    }
}

extern "C" void kernel_launch(void* const* d_in, const int* in_sizes, int n_in,
                              void* d_out, int out_size, void* d_ws, size_t ws_size,
                              hipStream_t stream) {
    const float* x   = (const float*)d_in[0];
    const float* w1  = (const float*)d_in[1];
    const float* b1  = (const float*)d_in[2];
    const float* w2  = (const float*)d_in[3];
    const float* b2  = (const float*)d_in[4];
    const float* wpe = (const float*)d_in[5];
    float* out = (float*)d_out;

    char* ws = (char*)d_ws;
    unsigned short* xb  = (unsigned short*)(ws);              // 16.78 MB
    unsigned short* w1t = (unsigned short*)(ws + 16777216);   //  6.29 MB
    unsigned short* w2t = (unsigned short*)(ws + 23068672);   //  2.10 MB
    unsigned short* Qb  = (unsigned short*)(ws + 25165824);   // 16.78 MB
    unsigned short* Kb  = (unsigned short*)(ws + 41943040);   // 16.78 MB
    unsigned short* Vb  = (unsigned short*)(ws + 58720256);   // 16.78 MB
    unsigned short* Yb  = (unsigned short*)(ws + 75497472);   // 16.78 MB -> 92.3 MB total

    k_f32_to_bf16<<<2048, 256, 0, stream>>>(x, xb, 8388608 / 8);
    k_transpose_bf16<<<768, 256, 0, stream>>>(w1, w1t, 1024, 3072);
    k_transpose_bf16<<<256, 256, 0, stream>>>(w2, w2t, 1024, 1024);
    k_gemm_ring<<<768, 512, 0, stream>>>(xb, w1t, b1, wpe, Qb, Kb, Vb,
                                         nullptr, 3072, 1024, 0);
    k_attn<<<2048, 256, 0, stream>>>(Qb, Kb, Vb, Yb);
    k_gemm_ring<<<256, 512, 0, stream>>>(Yb, w2t, b2, nullptr, nullptr, nullptr,
                                         nullptr, out, 1024, 1024, 1);
}